// Round 1
// baseline (425.103 us; speedup 1.0000x reference)
//
#include <hip/hip_runtime.h>
#include <hip/hip_bf16.h>

// Problem constants (match reference)
#define NN      1024      // num nodes
#define IN_DIM  16
#define HID     32
#define OUT_DIM 256
#define NE      8192      // edges (without self loops)
#define FDIM    (NN*HID)  // 32768
#define F4      (FDIM/4)  // 8192
#define F8      (FDIM/8)  // 4096

// ---------------- degree ----------------
__global__ void deg_init_k(float* __restrict__ deg) {
    int i = blockIdx.x * 256 + threadIdx.x;
    if (i < NN) deg[i] = 1.0f;              // self loop contributes 1
}

__global__ void deg_acc_k(const int* __restrict__ col, float* __restrict__ deg) {
    int e = blockIdx.x * 256 + threadIdx.x;
    if (e < NE) atomicAdd(&deg[col[e]], 1.0f);
}

// ---------------- fused matmul + selfloop/bias init ----------------
// in: [NN,K] pre-activation, W: [K,HID], bias: [HID]
// hW[n][f]  = act(in[n]) @ W
// tmp[n][f] = hW[n][f]/deg[n] + bias[f]     (self-loop term + bias)
__global__ void mat_conv_k(const float* __restrict__ in, const float* __restrict__ W,
                           const float* __restrict__ bias, const float* __restrict__ deg,
                           float* __restrict__ hW, float* __restrict__ tmp,
                           int K, int relu_in) {
    int idx = blockIdx.x * 256 + threadIdx.x;      // 0..NN*HID-1
    int n = idx >> 5;
    int f = idx & 31;
    float acc = 0.f;
    const float* xin = in + n * K;
    for (int k = 0; k < K; ++k) {
        float xv = xin[k];
        if (relu_in) xv = fmaxf(xv, 0.f);
        acc += xv * W[k * HID + f];
    }
    hW[idx]  = acc;
    tmp[idx] = acc / deg[n] + bias[f];
}

// ---------------- edge scatter: out[col] += hW[row]*norm ----------------
__global__ void conv_scatter_k(const int* __restrict__ row, const int* __restrict__ col,
                               const float* __restrict__ deg, const float* __restrict__ hW,
                               float* __restrict__ out) {
    int idx = blockIdx.x * 256 + threadIdx.x;      // e*HID + f
    int e = idx >> 5;
    int f = idx & 31;
    if (e >= NE) return;
    int r = row[e], c = col[e];
    float norm = 1.0f / sqrtf(deg[r] * deg[c]);
    atomicAdd(&out[c * HID + f], hW[r * HID + f] * norm);
}

// ---------------- residual: P = T + relu(P); optionally v = relu(P_new) ----------------
__global__ void residual_k(const float* __restrict__ T, float* __restrict__ P,
                           float* __restrict__ v, int writeV) {
    int i = blockIdx.x * 256 + threadIdx.x;
    if (i >= FDIM) return;
    float s = T[i] + fmaxf(P[i], 0.f);
    P[i] = s;
    if (writeV) v[i] = fmaxf(s, 0.f);
}

// ---------------- y = bias (init before atomic split-K accumulation) ----------------
__global__ void bias_init_k(const float* __restrict__ b, float* __restrict__ y, int n) {
    int i = blockIdx.x * 256 + threadIdx.x;
    if (i < n) y[i] = b[i];
}

// ---------------- split-K GEMV: y[j] += sum_i act(v[i]) * W[i][j] ----------------
// grid.x = col tiles (1024 cols each), grid.y = row splits (R rows each)
template<int RELU_V>
__global__ void gemv_k(const float* __restrict__ v, const float* __restrict__ W,
                       float* __restrict__ y, int rows, int cols, int R) {
    __shared__ float vs[256];
    int row0 = blockIdx.y * R;
    int col0 = blockIdx.x * 1024 + threadIdx.x * 4;
    for (int r = threadIdx.x; r < R; r += 256) {
        float t = v[row0 + r];
        vs[r] = RELU_V ? fmaxf(t, 0.f) : t;
    }
    __syncthreads();
    if (col0 < cols) {
        float4 acc = make_float4(0.f, 0.f, 0.f, 0.f);
        const float* Wp = W + (size_t)row0 * cols + col0;
        for (int r = 0; r < R; ++r) {
            float vi = vs[r];
            float4 w = *reinterpret_cast<const float4*>(Wp);
            acc.x += vi * w.x; acc.y += vi * w.y;
            acc.z += vi * w.z; acc.w += vi * w.w;
            Wp += cols;
        }
        atomicAdd(&y[col0 + 0], acc.x);
        atomicAdd(&y[col0 + 1], acc.y);
        atomicAdd(&y[col0 + 2], acc.z);
        atomicAdd(&y[col0 + 3], acc.w);
    }
}

// ---------------- softmax over 256 (single block, deterministic) ----------------
__global__ void softmax_k(const float* __restrict__ y, float* __restrict__ out) {
    __shared__ float s[OUT_DIM];
    int t = threadIdx.x;
    float val = y[t];
    s[t] = val;
    __syncthreads();
    float m = -INFINITY;
    for (int i = 0; i < OUT_DIM; ++i) m = fmaxf(m, s[i]);
    float e = expf(val - m);
    __syncthreads();
    s[t] = e;
    __syncthreads();
    float sum = 0.f;
    for (int i = 0; i < OUT_DIM; ++i) sum += s[i];
    out[t] = e / sum;
}

extern "C" void kernel_launch(void* const* d_in, const int* in_sizes, int n_in,
                              void* d_out, int out_size, void* d_ws, size_t ws_size,
                              hipStream_t stream) {
    const float* x    = (const float*)d_in[0];
    const int*   ei   = (const int*)  d_in[1];   // [2, NE]
    const float* W_in = (const float*)d_in[2];
    const float* b_in = (const float*)d_in[3];
    const float* Wb   = (const float*)d_in[4];   // [3,2,32,32]
    const float* bb   = (const float*)d_in[5];   // [3,2,32]
    const float* W1   = (const float*)d_in[6];   // [32768,8192]
    const float* b1   = (const float*)d_in[7];
    const float* W2   = (const float*)d_in[8];   // [8192,4096]
    const float* b2   = (const float*)d_in[9];
    const float* W3   = (const float*)d_in[10];  // [4096,256]
    const float* b3   = (const float*)d_in[11];
    float* out = (float*)d_out;

    const int* row = ei;
    const int* col = ei + NE;

    float* ws  = (float*)d_ws;
    float* deg = ws;               // 1024
    float* hW  = deg + NN;         // 32768
    float* P   = hW + FDIM;        // 32768
    float* T2  = P  + FDIM;        // 32768
    float* T3  = T2 + FDIM;        // 32768
    float* v   = T3 + FDIM;        // 32768
    float* y1  = v  + FDIM;        // 8192
    float* y2  = y1 + F4;          // 4096
    float* y3  = y2 + F8;          // 256

    // degrees (with self loops)
    deg_init_k<<<(NN + 255) / 256, 256, 0, stream>>>(deg);
    deg_acc_k<<<(NE + 255) / 256, 256, 0, stream>>>(col, deg);

    const int MAT_GRID  = (NN * HID) / 256;   // 128
    const int SCAT_GRID = (NE * HID) / 256;   // 1024

    // input conv: P = gcn(x, W_in, b_in)   (pre-relu)
    mat_conv_k<<<MAT_GRID, 256, 0, stream>>>(x, W_in, b_in, deg, hW, P, IN_DIM, 0);
    conv_scatter_k<<<SCAT_GRID, 256, 0, stream>>>(row, col, deg, hW, P);

    // residual blocks
    for (int blk = 0; blk < 3; ++blk) {
        const float* W0 = Wb + (size_t)(blk * 2 + 0) * HID * HID;
        const float* W1b = Wb + (size_t)(blk * 2 + 1) * HID * HID;
        const float* b0 = bb + (size_t)(blk * 2 + 0) * HID;
        const float* b1b = bb + (size_t)(blk * 2 + 1) * HID;

        // o1 = gcn(relu(P), W0, b0)  -> T2 (pre-relu)
        mat_conv_k<<<MAT_GRID, 256, 0, stream>>>(P, W0, b0, deg, hW, T2, HID, 1);
        conv_scatter_k<<<SCAT_GRID, 256, 0, stream>>>(row, col, deg, hW, T2);
        // o2 = gcn(relu(T2), W1b, b1b) -> T3 (no relu)
        mat_conv_k<<<MAT_GRID, 256, 0, stream>>>(T2, W1b, b1b, deg, hW, T3, HID, 1);
        conv_scatter_k<<<SCAT_GRID, 256, 0, stream>>>(row, col, deg, hW, T3);
        // P = T3 + relu(P); last block also writes v = relu(P_new)
        residual_k<<<MAT_GRID, 256, 0, stream>>>(T3, P, v, blk == 2 ? 1 : 0);
    }

    // MLP head: y1 = relu(v @ W1 + b1) etc. (relu deferred to consumer load)
    bias_init_k<<<(F4 + 255) / 256, 256, 0, stream>>>(b1, y1, F4);
    {
        dim3 g(F4 / 1024, FDIM / 128);   // (8, 256) = 2048 blocks
        gemv_k<0><<<g, 256, 0, stream>>>(v, W1, y1, FDIM, F4, 128);
    }
    bias_init_k<<<(F8 + 255) / 256, 256, 0, stream>>>(b2, y2, F8);
    {
        dim3 g(F8 / 1024, F4 / 32);      // (4, 256) = 1024 blocks
        gemv_k<1><<<g, 256, 0, stream>>>(y1, W2, y2, F4, F8, 32);
    }
    bias_init_k<<<(OUT_DIM + 255) / 256, 256, 0, stream>>>(b3, y3, OUT_DIM);
    {
        dim3 g(1, F8 / 32);              // (1, 128) = 128 blocks
        gemv_k<1><<<g, 256, 0, stream>>>(y2, W3, y3, F8, OUT_DIM, 32);
    }

    softmax_k<<<1, OUT_DIM, 0, stream>>>(y3, out);
}